// Round 1
// baseline (231.681 us; speedup 1.0000x reference)
//
#include <hip/hip_runtime.h>

#define N_NODES 100000
#define N_EDGES 3200000
#define N_GRAPHS 1024
#define NCLS 21
#define NBKT 782          // buckets of 128 nodes
#define CAP 4480          // padded bucket capacity (mean 4096, sigma 64 -> +6 sigma)
#define NB 512            // streaming blocks for binning
#define CHUNK 6250        // N_EDGES / NB
#define TROW 72           // LDS tile row stride in ushorts (144B: breaks b128 bank aliasing)

typedef short s8v __attribute__((ext_vector_type(8)));
typedef float f4v __attribute__((ext_vector_type(4)));
typedef float f2v __attribute__((ext_vector_type(2)));

__device__ __forceinline__ float bf2f(unsigned short u) {
    return __uint_as_float(((unsigned)u) << 16);
}
__device__ __forceinline__ unsigned short f2bf(float f) {
    unsigned u = __float_as_uint(f);
    unsigned r = 0x7fffu + ((u >> 16) & 1u);   // RNE
    return (unsigned short)((u + r) >> 16);
}
__device__ __forceinline__ float lo2f(unsigned w) { return __uint_as_float(w << 16); }
__device__ __forceinline__ float hi2f(unsigned w) { return __uint_as_float(w & 0xffff0000u); }
// unpack dword of 2 bf16 -> float2 {even, odd}; add becomes v_pk_add_f32
__device__ __forceinline__ f2v up2(unsigned w) {
    f2v r;
    r.x = __uint_as_float(w << 16);
    r.y = __uint_as_float(w & 0xffff0000u);
    return r;
}

// ---- fused prep: wp pack (blocks 0-31), gstart (32-36), gcur init (37) ----
__global__ void k_prep(const float* __restrict__ W2l, const float* __restrict__ W2r,
                       unsigned short* __restrict__ wp,
                       const int* __restrict__ batch, int* __restrict__ gstart,
                       int* __restrict__ gcur) {
    if (blockIdx.x < 32) {
        int tid = blockIdx.x * 256 + threadIdx.x;   // 8192 total
        int frag = tid >> 9;
        int r = tid & 511;
        int L = r >> 3, j = r & 7;
        int kstep = frag >> 2, nt = frag & 3;
        int k = kstep * 32 + (L >> 4) * 8 + j;
        int n = nt * 16 + (L & 15);
        float val = (k < 64) ? W2l[k * 64 + n] : W2r[(k - 64) * 64 + n];
        wp[tid] = f2bf(val);
    } else if (blockIdx.x < 37) {
        int g = (blockIdx.x - 32) * 256 + threadIdx.x;
        if (g > N_GRAPHS) return;
        if (g == N_GRAPHS) { gstart[N_GRAPHS] = N_NODES; return; }
        int lo = 0, hi = N_NODES;
        while (lo < hi) { int m = (lo + hi) >> 1; if (batch[m] < g) lo = m + 1; else hi = m; }
        gstart[g] = lo;
    } else {
        for (int i = threadIdx.x; i < NBKT; i += 256) gcur[i] = i * CAP;
    }
}

// ---- single-pass bin: LDS count -> global run reservation -> LDS scatter ----
__global__ __launch_bounds__(256) void k_binone(const int* __restrict__ src,
                                                const int* __restrict__ dst,
                                                int* __restrict__ gcur,
                                                unsigned int* __restrict__ bins) {
    __shared__ unsigned int ebuf[CHUNK];         // 25 KB
    __shared__ unsigned short bbuf[CHUNK];       // 12.5 KB
    __shared__ int lh[NBKT];
    __shared__ int lbase[NBKT];
    int t = threadIdx.x;
    for (int i = t; i < NBKT; i += 256) lh[i] = 0;
    __syncthreads();
    const int2* s2 = (const int2*)(src + blockIdx.x * CHUNK);
    const int2* d2 = (const int2*)(dst + blockIdx.x * CHUNK);
    for (int i = t; i < CHUNK / 2; i += 256) {
        int2 s = s2[i];
        int2 d = d2[i];
        uint2 pp;
        pp.x = ((unsigned)s.x << 7) | (unsigned)(d.x & 127);
        pp.y = ((unsigned)s.y << 7) | (unsigned)(d.y & 127);
        *(uint2*)(&ebuf[2 * i]) = pp;
        bbuf[2 * i]     = (unsigned short)(d.x >> 7);
        bbuf[2 * i + 1] = (unsigned short)(d.y >> 7);
        atomicAdd(&lh[d.x >> 7], 1);
        atomicAdd(&lh[d.y >> 7], 1);
    }
    __syncthreads();
    for (int i = t; i < NBKT; i += 256)
        lbase[i] = atomicAdd(&gcur[i], lh[i]);
    __syncthreads();
    for (int i = t; i < NBKT; i += 256) lh[i] = lbase[i];
    __syncthreads();
    for (int i = t; i < CHUNK; i += 256) {
        int b = (int)bbuf[i];
        int pos = atomicAdd(&lh[b], 1);
        if (pos < (b + 1) * CAP) bins[pos] = ebuf[i];
    }
}

// ---- per-bucket (128 nodes): slurp -> hist -> scan -> row/deg + CSR + layer-1 ----
__global__ __launch_bounds__(256) void k_build(
    const int* __restrict__ gcur, unsigned int* __restrict__ bins,
    int* __restrict__ row, unsigned short* __restrict__ deg,
    const float* __restrict__ x,
    const float* __restrict__ W1l, const float* __restrict__ b1,
    const float* __restrict__ W1r, unsigned short* __restrict__ h1b) {
    __shared__ unsigned int ebuf[CAP];   // 17.9 KB
    __shared__ int hist[128];
    __shared__ int curs[128];
    __shared__ int lds[128];
    __shared__ float t1[128];
    int k = blockIdx.x, t = threadIdx.x;
    int e0 = k * CAP;
    int cnt = min(gcur[k] - e0, CAP);
    if (t < 128) { hist[t] = 0; t1[t] = 0.0f; }
    __syncthreads();
    for (int i = t; i < cnt; i += 256) {
        unsigned p = bins[e0 + i];
        ebuf[i] = p;
        atomicAdd(&hist[p & 127u], 1);
    }
    __syncthreads();
    if (t < 128) lds[t] = hist[t];
    __syncthreads();
    for (int off = 1; off < 128; off <<= 1) {
        int cur = (t < 128) ? lds[t] : 0;
        int add = (t < 128 && t >= off) ? lds[t - off] : 0;
        __syncthreads();
        if (t < 128) lds[t] = cur + add;
        __syncthreads();
    }
    if (t < 128) {
        int run = e0 + lds[t] - hist[t];
        curs[t] = run;
        int n = k * 128 + t;
        if (n < N_NODES) { row[n] = run; deg[n] = (unsigned short)hist[t]; }
    }
    __syncthreads();
    for (int i = t; i < cnt; i += 256) {
        unsigned p = ebuf[i];
        int slot = (int)(p & 127u);
        int pos = atomicAdd(&curs[slot], 1);
        bins[pos] = p >> 7;
        atomicAdd(&t1[slot], x[p >> 7]);
    }
    __syncthreads();
    for (int i = t; i < 128 * 64; i += 256) {
        int slot = i >> 6, f = i & 63;
        int n = k * 128 + slot;
        if (n >= N_NODES) break;
        float a = t1[slot] / fmaxf((float)hist[slot], 1.0f);
        float v = a * W1l[f] + b1[f] + x[n] * W1r[f];
        h1b[(size_t)n * 64 + f] = f2bf(fmaxf(v, 0.0f));
    }
}

// ---- layer 2 FUSED: gather (per node) -> LDS tile -> MFMA GEMV -> h2b ----
// 8 nodes per wave (12500 waves -> residency pinned at 32 waves/CU cap).
// Wave pair (wid&~1) shares one 16-row tile; each wave MFMAs half the features.
__global__ __launch_bounds__(256) void k_l2f(
    const int* __restrict__ row, const unsigned short* __restrict__ deg,
    const unsigned int* __restrict__ csr,
    const unsigned short* __restrict__ h1b,
    const unsigned short* __restrict__ wp, const float* __restrict__ b2,
    unsigned short* __restrict__ h2b) {
    __shared__ unsigned short tile[2][16 * TROW];   // 4.5 KB
    int wid = threadIdx.x >> 6;
    int pair = wid >> 1, half = wid & 1;
    int tb = (blockIdx.x * 2 + pair) * 16;          // tile base node
    if (tb >= N_NODES) return;
    int L = threadIdx.x & 63;
    int fo = L & 7;
    int es = L >> 3;
    int fown = fo * 8 + es;            // feature this lane owns post-reduce
    unsigned short* tw = tile[pair];

    // preload row/deg for all 8 nodes (wave-uniform -> scalar loads, kills
    // the per-node chain-head latency stall)
    int r0a[8]; int dna[8];
#pragma unroll
    for (int t = 0; t < 8; t++) {
        int n = tb + half * 8 + t;
        r0a[t] = row[n];
        dna[t] = (int)deg[n];
    }

    for (int t = 0; t < 8; t++) {
        int r0 = r0a[t];
        int dn = dna[t];
        int r1 = r0 + dn;
        f2v p0 = {0.f, 0.f}, p1 = p0, p2 = p0, p3 = p0;
        int base = r0;
        for (; base + 32 <= r1; base += 32) {
            int sA = (int)csr[base + es];
            int sB = (int)csr[base + 8 + es];
            int sC = (int)csr[base + 16 + es];
            int sD = (int)csr[base + 24 + es];
            uint4 dA = *(const uint4*)(h1b + (size_t)sA * 64 + fo * 8);
            uint4 dB = *(const uint4*)(h1b + (size_t)sB * 64 + fo * 8);
            uint4 dC = *(const uint4*)(h1b + (size_t)sC * 64 + fo * 8);
            uint4 dD = *(const uint4*)(h1b + (size_t)sD * 64 + fo * 8);
            p0 += up2(dA.x); p1 += up2(dA.y); p2 += up2(dA.z); p3 += up2(dA.w);
            p0 += up2(dB.x); p1 += up2(dB.y); p2 += up2(dB.z); p3 += up2(dB.w);
            p0 += up2(dC.x); p1 += up2(dC.y); p2 += up2(dC.z); p3 += up2(dC.w);
            p0 += up2(dD.x); p1 += up2(dD.y); p2 += up2(dD.z); p3 += up2(dD.w);
        }
        for (; base + 16 <= r1; base += 16) {
            int sA = (int)csr[base + es];
            int sB = (int)csr[base + 8 + es];
            uint4 dA = *(const uint4*)(h1b + (size_t)sA * 64 + fo * 8);
            uint4 dB = *(const uint4*)(h1b + (size_t)sB * 64 + fo * 8);
            p0 += up2(dA.x); p1 += up2(dA.y); p2 += up2(dA.z); p3 += up2(dA.w);
            p0 += up2(dB.x); p1 += up2(dB.y); p2 += up2(dB.z); p3 += up2(dB.w);
        }
        for (; base < r1; base += 8) {
            int e = base + es;
            bool act = e < r1;
            int sA = (int)csr[act ? e : r1 - 1];
            uint4 d = *(const uint4*)(h1b + (size_t)sA * 64 + fo * 8);
            unsigned m = act ? 0xffffffffu : 0u;
            d.x &= m; d.y &= m; d.z &= m; d.w &= m;
            p0 += up2(d.x); p1 += up2(d.y); p2 += up2(d.z); p3 += up2(d.w);
        }
        // 3-stage 8->1 feature reduce across es, on float2 pairs
        {
            bool hi = (es & 4) != 0;
            f2v s0 = hi ? p0 : p2, s1 = hi ? p1 : p3;
            f2v r0v, r1v;
            r0v.x = __shfl_xor(s0.x, 32, 64); r0v.y = __shfl_xor(s0.y, 32, 64);
            r1v.x = __shfl_xor(s1.x, 32, 64); r1v.y = __shfl_xor(s1.y, 32, 64);
            p0 = (hi ? p2 : p0) + r0v;
            p1 = (hi ? p3 : p1) + r1v;
        }
        {
            bool hi = (es & 2) != 0;
            f2v s0 = hi ? p0 : p1;
            f2v rv;
            rv.x = __shfl_xor(s0.x, 16, 64); rv.y = __shfl_xor(s0.y, 16, 64);
            p0 = (hi ? p1 : p0) + rv;
        }
        float a0;
        {
            bool hi = (es & 1) != 0;
            float s = hi ? p0.x : p0.y;   // send the element the partner needs
            float rv = __shfl_xor(s, 8, 64);
            a0 = (hi ? p0.y : p0.x) + rv;
        }
        float inv = 1.0f / fmaxf((float)dn, 1.0f);
        tw[(half * 8 + t) * TROW + fown] = f2bf(a0 * inv);   // 2B/lane, 2-way bank = free
    }
    __syncthreads();

    // ---- MFMA phase: each wave of the pair does half the feature columns ----
    int m = L & 15, q = L >> 4;
    int nrow = tb + m;

    const s8v a0 = *(const s8v*)(tw + m * TROW + q * 8);
    const s8v a1 = *(const s8v*)(tw + m * TROW + 32 + q * 8);
    const s8v a2 = *(const s8v*)(h1b + (size_t)nrow * 64 + q * 8);
    const s8v a3 = *(const s8v*)(h1b + (size_t)nrow * 64 + 32 + q * 8);

    int nt0 = half * 2, nt1 = nt0 + 1;
    const unsigned short* wpb = wp + (size_t)L * 8;
    s8v B00 = *(const s8v*)(wpb + (size_t)(nt0)      * 512);
    s8v B01 = *(const s8v*)(wpb + (size_t)(nt0 + 4)  * 512);
    s8v B02 = *(const s8v*)(wpb + (size_t)(nt0 + 8)  * 512);
    s8v B03 = *(const s8v*)(wpb + (size_t)(nt0 + 12) * 512);
    s8v B10 = *(const s8v*)(wpb + (size_t)(nt1)      * 512);
    s8v B11 = *(const s8v*)(wpb + (size_t)(nt1 + 4)  * 512);
    s8v B12 = *(const s8v*)(wpb + (size_t)(nt1 + 8)  * 512);
    s8v B13 = *(const s8v*)(wpb + (size_t)(nt1 + 12) * 512);

    f4v acc0 = {0.f, 0.f, 0.f, 0.f}, acc1 = acc0;
    acc0 = __builtin_amdgcn_mfma_f32_16x16x32_bf16(a0, B00, acc0, 0, 0, 0);
    acc0 = __builtin_amdgcn_mfma_f32_16x16x32_bf16(a1, B01, acc0, 0, 0, 0);
    acc0 = __builtin_amdgcn_mfma_f32_16x16x32_bf16(a2, B02, acc0, 0, 0, 0);
    acc0 = __builtin_amdgcn_mfma_f32_16x16x32_bf16(a3, B03, acc0, 0, 0, 0);
    acc1 = __builtin_amdgcn_mfma_f32_16x16x32_bf16(a0, B10, acc1, 0, 0, 0);
    acc1 = __builtin_amdgcn_mfma_f32_16x16x32_bf16(a1, B11, acc1, 0, 0, 0);
    acc1 = __builtin_amdgcn_mfma_f32_16x16x32_bf16(a2, B12, acc1, 0, 0, 0);
    acc1 = __builtin_amdgcn_mfma_f32_16x16x32_bf16(a3, B13, acc1, 0, 0, 0);

    int fcol = L & 15;
    float bia0 = b2[nt0 * 16 + fcol], bia1 = b2[nt1 * 16 + fcol];
    int rbase = tb + q * 4;
#pragma unroll
    for (int r = 0; r < 4; r++) {
        size_t o = (size_t)(rbase + r) * 64 + fcol;
        h2b[o + nt0 * 16] = f2bf(fmaxf(acc0[r] + bia0, 0.0f));
        h2b[o + nt1 * 16] = f2bf(fmaxf(acc1[r] + bia1, 0.0f));
    }
}

// ---- head: block per graph — pool h2 rows + classify, no global intermediates ----
__global__ __launch_bounds__(256) void k_head(
    const unsigned short* __restrict__ h2b, const int* __restrict__ gstart,
    const float* __restrict__ Wc, const float* __restrict__ bc,
    float* __restrict__ out) {
    __shared__ float part[4][64];
    __shared__ float rowv[64];
    int g = blockIdx.x;
    int wid = threadIdx.x >> 6;
    int f = threadIdx.x & 63;
    int ns = gstart[g], ne = gstart[g + 1];
    float s = 0.0f;
    int n = ns + wid;
    for (; n + 12 < ne; n += 16) {
        float v0 = bf2f(h2b[(size_t)(n)      * 64 + f]);
        float v1 = bf2f(h2b[(size_t)(n + 4)  * 64 + f]);
        float v2 = bf2f(h2b[(size_t)(n + 8)  * 64 + f]);
        float v3 = bf2f(h2b[(size_t)(n + 12) * 64 + f]);
        s += (v0 + v1) + (v2 + v3);
    }
    for (; n < ne; n += 4) s += bf2f(h2b[(size_t)n * 64 + f]);
    part[wid][f] = s;
    __syncthreads();
    if (threadIdx.x < 64) {
        float tot = part[0][f] + part[1][f] + part[2][f] + part[3][f];
        rowv[f] = tot / fmaxf((float)(ne - ns), 1.0f);
    }
    __syncthreads();
    if (threadIdx.x < NCLS) {
        float acc = bc[threadIdx.x];
#pragma unroll
        for (int kk = 0; kk < 64; kk++) acc += rowv[kk] * Wc[kk * NCLS + threadIdx.x];
        out[g * NCLS + threadIdx.x] = acc;
    }
}

extern "C" void kernel_launch(void* const* d_in, const int* in_sizes, int n_in,
                              void* d_out, int out_size, void* d_ws, size_t ws_size,
                              hipStream_t stream) {
    const float* x     = (const float*)d_in[0];
    const int*   eidx  = (const int*)d_in[1];
    const int*   batch = (const int*)d_in[2];
    const float* W1l   = (const float*)d_in[3];
    const float* b1    = (const float*)d_in[4];
    const float* W1r   = (const float*)d_in[5];
    const float* W2l   = (const float*)d_in[6];
    const float* b2    = (const float*)d_in[7];
    const float* W2r   = (const float*)d_in[8];
    const float* Wc    = (const float*)d_in[9];
    const float* bc    = (const float*)d_in[10];
    float* out = (float*)d_out;

    const int* src = eidx;
    const int* dst = eidx + N_EDGES;

    // workspace ≈ 40.3 MB (R16 passed with this footprint)
    char* p = (char*)d_ws;
    unsigned int* bins  = (unsigned int*)p;     p += (size_t)NBKT * CAP * 4;     // 14.0 MB
    unsigned short* h1b = (unsigned short*)p;   p += (size_t)N_NODES * 64 * 2;   // 12.8 MB
    unsigned short* h2b = (unsigned short*)p;   p += (size_t)N_NODES * 64 * 2;   // 12.8 MB
    int* row   = (int*)p;                       p += (size_t)(N_NODES + 1) * 4;  // 0.40 MB
    unsigned short* deg = (unsigned short*)p;   p += (size_t)N_NODES * 2;        // 0.20 MB
    int* gcur  = (int*)p;                       p += NBKT * 4;
    int* gstart= (int*)p;                       p += (N_GRAPHS + 1) * 4;
    unsigned short* wp = (unsigned short*)p;    p += 8192 * 2;                   // 16 KB

    k_prep  <<<38, 256, 0, stream>>>(W2l, W2r, wp, batch, gstart, gcur);
    k_binone<<<NB, 256, 0, stream>>>(src, dst, gcur, bins);
    k_build <<<NBKT, 256, 0, stream>>>(gcur, bins, row, deg, x, W1l, b1, W1r, h1b);
    k_l2f   <<<(N_NODES / 32), 256, 0, stream>>>(row, deg, bins, h1b, wp, b2, h2b);
    k_head  <<<N_GRAPHS, 256, 0, stream>>>(h2b, gstart, Wc, bc, out);
}